// Round 1
// baseline (450.803 us; speedup 1.0000x reference)
//
#include <hip/hip_runtime.h>
#include <math.h>

// Problem constants (from reference): N=2, D=384, 2U=256, nH=8, hd=48, nL=4, nP=4
#define DM   384
#define U2   256
#define NH   8
#define HD   48
#define NL   4
#define NP   4

// =====================================================================
// Generic f32 GEMM with bias: C(M x N, ldc) = A(M x K, lda) @ B(K x N, ldb) + bias
// Tiles: 64x64 output per block, BK=16, 256 threads, 4x4 acc per thread.
// Requires M%64==0, N%64==0, K%16==0 (true for all shapes here).
// =====================================================================
__global__ __launch_bounds__(256) void gemm_bias_kernel(
    const float* __restrict__ A, int lda,
    const float* __restrict__ B, int ldb,
    const float* __restrict__ bias,
    float* __restrict__ C, int ldc,
    int K)
{
    __shared__ float As[16][64];   // transposed A tile: As[k][m]
    __shared__ float Bs[16][64];   // Bs[k][n]

    const int t  = threadIdx.x;
    const int bm = blockIdx.x * 64;
    const int bn = blockIdx.y * 64;
    const int ty = t >> 4;          // 0..15 -> row group
    const int tx = t & 15;          // 0..15 -> col group
    const int ar = t >> 2;          // 0..63  A tile row
    const int ak = (t & 3) << 2;    // 0,4,8,12  A tile k (float4)
    const int bk = t >> 4;          // 0..15  B tile k
    const int b4 = (t & 15) << 2;   // 0..60  B tile n (float4)

    const float* Aptr = A + (size_t)(bm + ar) * lda + ak;
    const float* Bptr = B + (size_t)bk * ldb + bn + b4;

    float acc[4][4] = {};

    for (int k0 = 0; k0 < K; k0 += 16) {
        const float4 av = *(const float4*)(Aptr + k0);
        const float4 bv = *(const float4*)(Bptr + (size_t)k0 * ldb);
        As[ak + 0][ar] = av.x;
        As[ak + 1][ar] = av.y;
        As[ak + 2][ar] = av.z;
        As[ak + 3][ar] = av.w;
        *(float4*)&Bs[bk][b4] = bv;
        __syncthreads();
#pragma unroll
        for (int kk = 0; kk < 16; ++kk) {
            float a[4], b[4];
            *(float4*)a = *(const float4*)&As[kk][ty << 2];
            *(float4*)b = *(const float4*)&Bs[kk][tx << 2];
#pragma unroll
            for (int i = 0; i < 4; ++i)
#pragma unroll
                for (int j = 0; j < 4; ++j)
                    acc[i][j] = fmaf(a[i], b[j], acc[i][j]);
        }
        __syncthreads();
    }

    const float4 bb = *(const float4*)&bias[bn + (tx << 2)];
#pragma unroll
    for (int i = 0; i < 4; ++i) {
        float4 o;
        o.x = acc[i][0] + bb.x;
        o.y = acc[i][1] + bb.y;
        o.z = acc[i][2] + bb.z;
        o.w = acc[i][3] + bb.w;
        *(float4*)&C[(size_t)(bm + (ty << 2) + i) * ldc + bn + (tx << 2)] = o;
    }
}

// =====================================================================
// Fused sampler: per block = one (n, q).
//   - computes loc from reference_points + off (shared by both branches)
//   - softmaxes top/bot logits (16-wide per head)
//   - bilinear-gathers from val_top and val_bot with shared indices/weights
// 192 threads: head h = t/24, channel pair c2 = (t%24)*2 (hd=48 -> 24 float2)
// =====================================================================
__global__ __launch_bounds__(192) void sampler_kernel(
    const float* __restrict__ off_buf,    // (M, 256)
    const float* __restrict__ logit_top,  // (M, 128)
    const float* __restrict__ logit_bot,  // (M, 128)
    const float* __restrict__ ref_pts,    // (M, 4, 2)
    const int*   __restrict__ ss,         // (4,2) [H,W]
    const int*   __restrict__ lsi,        // (4,)
    const float* __restrict__ val_top,    // (Mv, 384)
    const float* __restrict__ val_bot,    // (Mv, 384)
    float* __restrict__ core_top,         // (M, 384)
    float* __restrict__ core_bot,         // (M, 384)
    int Lq, int LenIn)
{
    __shared__ int   sIdx[128][4];
    __shared__ float sW[128][4];
    __shared__ float sLt[128], sLb[128];
    __shared__ float sAt[128], sAb[128];

    const int bid = blockIdx.x;       // n*Lq + q
    const int n   = bid / Lq;
    const int t   = threadIdx.x;

    // ---- phase 1: geometry + raw logits (one thread per (h,l,p)) ----
    if (t < 128) {
        const int l = (t >> 2) & 3;
        // off col = ((h*4+l)*4+p)*2 == t*2 since t = h*16 + l*4 + p
        const float2 offv = *(const float2*)&off_buf[(size_t)bid * 256 + 2 * t];
        const float rx = ref_pts[(size_t)(bid * 4 + l) * 2 + 0];
        const float ry = ref_pts[(size_t)(bid * 4 + l) * 2 + 1];
        const int H = ss[2 * l], W = ss[2 * l + 1];
        const int start = lsi[l];

        const float x = (rx + offv.x / (float)W) * (float)W - 0.5f;
        const float y = (ry + offv.y / (float)H) * (float)H - 0.5f;
        const float x0f = floorf(x), y0f = floorf(y);
        const float lx = x - x0f, ly = y - y0f;
        const int ix0 = (int)x0f, iy0 = (int)y0f;
        const int ix1 = ix0 + 1,  iy1 = iy0 + 1;

        const float vx0 = (ix0 >= 0 && ix0 < W) ? 1.f : 0.f;
        const float vx1 = (ix1 >= 0 && ix1 < W) ? 1.f : 0.f;
        const float vy0 = (iy0 >= 0 && iy0 < H) ? 1.f : 0.f;
        const float vy1 = (iy1 >= 0 && iy1 < H) ? 1.f : 0.f;
        const int cx0 = min(max(ix0, 0), W - 1);
        const int cx1 = min(max(ix1, 0), W - 1);
        const int cy0 = min(max(iy0, 0), H - 1);
        const int cy1 = min(max(iy1, 0), H - 1);
        const int base = n * LenIn + start;

        sIdx[t][0] = base + cy0 * W + cx0;
        sIdx[t][1] = base + cy0 * W + cx1;
        sIdx[t][2] = base + cy1 * W + cx0;
        sIdx[t][3] = base + cy1 * W + cx1;
        sW[t][0] = (1.f - lx) * (1.f - ly) * vx0 * vy0;
        sW[t][1] = lx * (1.f - ly) * vx1 * vy0;
        sW[t][2] = (1.f - lx) * ly * vx0 * vy1;
        sW[t][3] = lx * ly * vx1 * vy1;

        sLt[t] = logit_top[(size_t)bid * 128 + t];
        sLb[t] = logit_bot[(size_t)bid * 128 + t];
    }
    __syncthreads();

    // ---- phase 2: softmax over 16 (l,p) per head; threads 0..7 top, 8..15 bot
    if (t < 16) {
        const int h = t & 7;
        const float* L = (t < 8) ? sLt : sLb;
        float* Aout    = (t < 8) ? sAt : sAb;
        float m = -1e30f;
        for (int j = 0; j < 16; ++j) m = fmaxf(m, L[h * 16 + j]);
        float e[16];
        float s = 0.f;
        for (int j = 0; j < 16; ++j) { e[j] = expf(L[h * 16 + j] - m); s += e[j]; }
        const float inv = 1.f / s;
        for (int j = 0; j < 16; ++j) Aout[h * 16 + j] = e[j] * inv;
    }
    __syncthreads();

    // ---- phase 3: gather + weighted accumulate (both branches) ----
    const int h  = t / 24;
    const int c2 = (t % 24) * 2;
    const int colbase = h * HD + c2;

    float atx = 0.f, aty = 0.f, abx = 0.f, aby = 0.f;
    for (int lp = 0; lp < 16; ++lp) {
        const int e = h * 16 + lp;
        const float wat = sAt[e];
        const float wab = sAb[e];
        float ptx = 0.f, pty = 0.f, pbx = 0.f, pby = 0.f;
#pragma unroll
        for (int k = 0; k < 4; ++k) {
            const float w = sW[e][k];
            const size_t idx = (size_t)sIdx[e][k] * DM + colbase;
            const float2 vt = *(const float2*)&val_top[idx];
            const float2 vb = *(const float2*)&val_bot[idx];
            ptx = fmaf(w, vt.x, ptx);
            pty = fmaf(w, vt.y, pty);
            pbx = fmaf(w, vb.x, pbx);
            pby = fmaf(w, vb.y, pby);
        }
        atx = fmaf(wat, ptx, atx);
        aty = fmaf(wat, pty, aty);
        abx = fmaf(wab, pbx, abx);
        aby = fmaf(wab, pby, aby);
    }
    float2 ot; ot.x = atx; ot.y = aty;
    float2 ob; ob.x = abx; ob.y = aby;
    *(float2*)&core_top[(size_t)bid * DM + colbase] = ot;
    *(float2*)&core_bot[(size_t)bid * DM + colbase] = ob;
}

// =====================================================================
// Host launcher
// =====================================================================
extern "C" void kernel_launch(void* const* d_in, const int* in_sizes, int n_in,
                              void* d_out, int out_size, void* d_ws, size_t ws_size,
                              hipStream_t stream) {
    const float* query   = (const float*)d_in[0];   // (2, Lq, 384)
    const float* refpts  = (const float*)d_in[1];   // (2, Lq, 4, 2)
    const float* flat    = (const float*)d_in[2];   // (2, LenIn, 384)
    const int*   ss      = (const int*)d_in[3];     // (4,2)
    const int*   lsi     = (const int*)d_in[4];     // (4,)
    const float* W_off   = (const float*)d_in[5];   // (256,256)
    const float* b_off   = (const float*)d_in[6];
    const float* W_attn  = (const float*)d_in[7];   // (256,128)
    const float* b_attn  = (const float*)d_in[8];
    const float* W_val   = (const float*)d_in[9];   // (256,384)
    const float* b_val   = (const float*)d_in[10];
    const float* W_out   = (const float*)d_in[11];  // (384,256)
    const float* b_out   = (const float*)d_in[12];
    const float* W_attn_zd = (const float*)d_in[13];// (384,128)
    const float* b_attn_zd = (const float*)d_in[14];
    const float* W_val_zd  = (const float*)d_in[15];// (384,384)
    const float* b_val_zd  = (const float*)d_in[16];
    const float* W_out_zd  = (const float*)d_in[17];// (384,128)
    const float* b_out_zd  = (const float*)d_in[18];

    const int Lq    = in_sizes[0] / (2 * DM);   // 5440
    const int LenIn = in_sizes[2] / (2 * DM);   // 5440
    const int M  = 2 * Lq;      // 10880 query rows
    const int Mv = 2 * LenIn;   // 10880 value rows

    float* out = (float*)d_out; // (2, Lq, 384): cols [0,256)=top, [256,384)=bot

    // workspace layout (floats)
    float* ws      = (float*)d_ws;
    float* off_buf = ws;                            // M*256
    float* lt      = off_buf + (size_t)M * 256;     // M*128
    float* lb      = lt + (size_t)M * 128;          // M*128
    float* vt      = lb + (size_t)M * 128;          // Mv*384
    float* vb      = vt + (size_t)Mv * 384;         // Mv*384
    float* ct      = vb + (size_t)Mv * 384;         // M*384
    float* cb      = ct + (size_t)M * 384;          // M*384

    const dim3 blk(256);
    const int mgrid  = M / 64;    // 170
    const int mvgrid = Mv / 64;   // 170

    // P1: off = query[:, :256] @ W_off + b_off        -> (M,256)
    gemm_bias_kernel<<<dim3(mgrid, 4), blk, 0, stream>>>(
        query, DM, W_off, 256, b_off, off_buf, 256, U2);
    // P2: logits_top = query[:, :256] @ W_attn + b_attn -> (M,128)
    gemm_bias_kernel<<<dim3(mgrid, 2), blk, 0, stream>>>(
        query, DM, W_attn, 128, b_attn, lt, 128, U2);
    // P3: logits_bot = query @ W_attn_zd + b_attn_zd    -> (M,128)
    gemm_bias_kernel<<<dim3(mgrid, 2), blk, 0, stream>>>(
        query, DM, W_attn_zd, 128, b_attn_zd, lb, 128, DM);
    // P4: val_top = flat[:, :256] @ W_val + b_val       -> (Mv,384)
    gemm_bias_kernel<<<dim3(mvgrid, 6), blk, 0, stream>>>(
        flat, DM, W_val, 384, b_val, vt, 384, U2);
    // P5: val_bot = flat @ W_val_zd + b_val_zd          -> (Mv,384)
    gemm_bias_kernel<<<dim3(mvgrid, 6), blk, 0, stream>>>(
        flat, DM, W_val_zd, 384, b_val_zd, vb, 384, DM);

    // P6: fused loc/softmax/bilinear sampling for both branches
    sampler_kernel<<<dim3(M), dim3(192), 0, stream>>>(
        off_buf, lt, lb, refpts, ss, lsi, vt, vb, ct, cb, Lq, LenIn);

    // P7: out[:, :256] = core_top @ W_out + b_out
    gemm_bias_kernel<<<dim3(mgrid, 4), blk, 0, stream>>>(
        ct, DM, W_out, 256, b_out, out, DM, DM);
    // P8: out[:, 256:384] = core_bot @ W_out_zd + b_out_zd
    gemm_bias_kernel<<<dim3(mgrid, 2), blk, 0, stream>>>(
        cb, DM, W_out_zd, 128, b_out_zd, out + U2, DM, DM);
}

// Round 2
// 303.563 us; speedup vs baseline: 1.4850x; 1.4850x over previous
//
#include <hip/hip_runtime.h>
#include <hip/hip_bf16.h>
#include <math.h>

// Problem constants: N=2, D=384, 2U=256, nH=8, hd=48, nL=4, nP=4
#define DM   384
#define U2   256
#define NH   8
#define HD   48

typedef __attribute__((ext_vector_type(8))) short short8;   // 8 bf16 = 4 VGPR
typedef __attribute__((ext_vector_type(4))) float floatx4;  // MFMA acc

static __device__ __forceinline__ unsigned short f2bfbits(float f) {
    __hip_bfloat16 h = __float2bfloat16(f);
    return *reinterpret_cast<unsigned short*>(&h);
}
static __device__ __forceinline__ float bflo(unsigned u) { return __uint_as_float(u << 16); }
static __device__ __forceinline__ float bfhi(unsigned u) { return __uint_as_float(u & 0xffff0000u); }

// =====================================================================
// fp32 GEMM with bias (kept for the offset projection P1 — geometry-
// sensitive path stays fp32). 64x64 tile, BK=16, 256 thr, 4x4 acc.
// =====================================================================
__global__ __launch_bounds__(256) void gemm_bias_kernel(
    const float* __restrict__ A, int lda,
    const float* __restrict__ B, int ldb,
    const float* __restrict__ bias,
    float* __restrict__ C, int ldc,
    int K)
{
    __shared__ float As[16][64];
    __shared__ float Bs[16][64];

    const int t  = threadIdx.x;
    const int bm = blockIdx.x * 64;
    const int bn = blockIdx.y * 64;
    const int ty = t >> 4, tx = t & 15;
    const int ar = t >> 2, ak = (t & 3) << 2;
    const int bk = t >> 4, b4 = (t & 15) << 2;

    const float* Aptr = A + (size_t)(bm + ar) * lda + ak;
    const float* Bptr = B + (size_t)bk * ldb + bn + b4;

    float acc[4][4] = {};
    for (int k0 = 0; k0 < K; k0 += 16) {
        const float4 av = *(const float4*)(Aptr + k0);
        const float4 bv = *(const float4*)(Bptr + (size_t)k0 * ldb);
        As[ak + 0][ar] = av.x; As[ak + 1][ar] = av.y;
        As[ak + 2][ar] = av.z; As[ak + 3][ar] = av.w;
        *(float4*)&Bs[bk][b4] = bv;
        __syncthreads();
#pragma unroll
        for (int kk = 0; kk < 16; ++kk) {
            float a[4], b[4];
            *(float4*)a = *(const float4*)&As[kk][ty << 2];
            *(float4*)b = *(const float4*)&Bs[kk][tx << 2];
#pragma unroll
            for (int i = 0; i < 4; ++i)
#pragma unroll
                for (int j = 0; j < 4; ++j)
                    acc[i][j] = fmaf(a[i], b[j], acc[i][j]);
        }
        __syncthreads();
    }
    const float4 bb = *(const float4*)&bias[bn + (tx << 2)];
#pragma unroll
    for (int i = 0; i < 4; ++i) {
        float4 o;
        o.x = acc[i][0] + bb.x; o.y = acc[i][1] + bb.y;
        o.z = acc[i][2] + bb.z; o.w = acc[i][3] + bb.w;
        *(float4*)&C[(size_t)(bm + (ty << 2) + i) * ldc + bn + (tx << 2)] = o;
    }
}

// =====================================================================
// Weight transpose + fp32->bf16 convert (once per launch, 6 weights).
// src: row-major (K x N) fp32 -> dst: (N x K) bf16.
// =====================================================================
struct WtAll {
    const float* src[6];
    __hip_bfloat16* dst[6];
    int K[6], N[6], off[7];
};
__global__ __launch_bounds__(256) void wt_kernel(WtAll d) {
    const int idx = blockIdx.x * 256 + threadIdx.x;
    if (idx >= d.off[6]) return;
    int s = 0;
#pragma unroll
    for (int i = 1; i < 6; ++i) if (idx >= d.off[i]) s = i;
    const int r = idx - d.off[s];
    const int k = r / d.N[s], n = r - k * d.N[s];
    d.dst[s][(size_t)n * d.K[s] + k] = __float2bfloat16(d.src[s][r]);
}

// =====================================================================
// bf16 MFMA GEMM: C(M x N) = A_f32(M x K) @ Wt_bf16(N x K)^T + bias.
// 128x128 tile, BK=32, 256 thr (4 waves 2x2 of 64x64), 16x16x32 MFMA.
// A converted fp32->bf16 during LDS staging. LDS rows padded to 40
// elements (80 B) so fragment ds_read_b128 is 2-way max (free).
// M%128==0, N%128==0, K%32==0.
// =====================================================================
template <typename OutT>
__global__ __launch_bounds__(256) void gemm_mfma_kernel(
    const float* __restrict__ A, int lda,
    const __hip_bfloat16* __restrict__ Bt, int ldbt,   // (N x K) bf16
    const float* __restrict__ bias,
    OutT* __restrict__ C, int ldc,
    int K)
{
    __shared__ __hip_bfloat16 As[128 * 40];
    __shared__ __hip_bfloat16 Bs[128 * 40];

    const int t    = threadIdx.x;
    const int bm   = blockIdx.x * 128;
    const int bn   = blockIdx.y * 128;
    const int w    = t >> 6, lane = t & 63;
    const int wm   = (w >> 1) * 64, wn = (w & 1) * 64;
    const int quad = lane >> 4, lm = lane & 15;

    // staging maps
    const int am = t >> 3;            // A row 0..31 (+32*i)
    const int ak = (t & 7) * 4;       // A k offset (float4)
    const int bn_ = t & 127;          // B row n
    const int bk0 = (t >> 7) * 8;     // B k offset base (0 or 8)

    floatx4 acc[4][4] = {};

    for (int k0 = 0; k0 < K; k0 += 32) {
        // ---- stage A (fp32 -> bf16) ----
#pragma unroll
        for (int i = 0; i < 4; ++i) {
            const int m = am + 32 * i;
            const float4 av = *(const float4*)&A[(size_t)(bm + m) * lda + k0 + ak];
            unsigned short* p = (unsigned short*)&As[m * 40 + ak];
            p[0] = f2bfbits(av.x); p[1] = f2bfbits(av.y);
            p[2] = f2bfbits(av.z); p[3] = f2bfbits(av.w);
        }
        // ---- stage B (bf16 transposed weights, 16B rows) ----
#pragma unroll
        for (int p = 0; p < 2; ++p) {
            const int k = bk0 + 16 * p;
            *(short8*)&Bs[bn_ * 40 + k] =
                *(const short8*)&Bt[(size_t)(bn + bn_) * ldbt + k0 + k];
        }
        __syncthreads();

        short8 af[4], bf[4];
#pragma unroll
        for (int i = 0; i < 4; ++i)
            af[i] = *(const short8*)&As[(wm + i * 16 + lm) * 40 + quad * 8];
#pragma unroll
        for (int j = 0; j < 4; ++j)
            bf[j] = *(const short8*)&Bs[(wn + j * 16 + lm) * 40 + quad * 8];
#pragma unroll
        for (int i = 0; i < 4; ++i)
#pragma unroll
            for (int j = 0; j < 4; ++j)
                acc[i][j] = __builtin_amdgcn_mfma_f32_16x16x32_bf16(
                    af[i], bf[j], acc[i][j], 0, 0, 0);
        __syncthreads();
    }

    // ---- epilogue: C[row = quad*4+reg (+i*16), col = lm (+j*16)] ----
#pragma unroll
    for (int i = 0; i < 4; ++i) {
#pragma unroll
        for (int reg = 0; reg < 4; ++reg) {
            const int row = bm + wm + i * 16 + quad * 4 + reg;
#pragma unroll
            for (int j = 0; j < 4; ++j) {
                const int col = bn + wn + j * 16 + lm;
                const float v = acc[i][j][reg] + bias[col];
                if constexpr (__is_same(OutT, float)) {
                    C[(size_t)row * ldc + col] = v;
                } else {
                    C[(size_t)row * ldc + col] = __float2bfloat16(v);
                }
            }
        }
    }
}

// =====================================================================
// Fused sampler: geometry + dual softmax + dual bilinear gather (bf16 vals)
// =====================================================================
__global__ __launch_bounds__(192) void sampler_kernel(
    const float* __restrict__ off_buf,    // (M, 256) fp32
    const float* __restrict__ logit_top,  // (M, 128)
    const float* __restrict__ logit_bot,  // (M, 128)
    const float* __restrict__ ref_pts,    // (M, 4, 2)
    const int*   __restrict__ ss,         // (4,2) [H,W]
    const int*   __restrict__ lsi,        // (4,)
    const __hip_bfloat16* __restrict__ val_top,  // (Mv, 384) bf16
    const __hip_bfloat16* __restrict__ val_bot,  // (Mv, 384) bf16
    float* __restrict__ core_top,         // (M, 384)
    float* __restrict__ core_bot,         // (M, 384)
    int Lq, int LenIn)
{
    __shared__ int   sIdx[128][5];   // stride 5: breaks the 3-head same-bank alias
    __shared__ float sW[128][5];
    __shared__ float sLt[128], sLb[128];
    __shared__ float sAt[128], sAb[128];

    const int bid = blockIdx.x;
    const int n   = bid / Lq;
    const int t   = threadIdx.x;

    if (t < 128) {
        const int l = (t >> 2) & 3;
        const float2 offv = *(const float2*)&off_buf[(size_t)bid * 256 + 2 * t];
        const float rx = ref_pts[(size_t)(bid * 4 + l) * 2 + 0];
        const float ry = ref_pts[(size_t)(bid * 4 + l) * 2 + 1];
        const int H = ss[2 * l], W = ss[2 * l + 1];
        const int start = lsi[l];

        const float x = (rx + offv.x / (float)W) * (float)W - 0.5f;
        const float y = (ry + offv.y / (float)H) * (float)H - 0.5f;
        const float x0f = floorf(x), y0f = floorf(y);
        const float lx = x - x0f, ly = y - y0f;
        const int ix0 = (int)x0f, iy0 = (int)y0f;
        const int ix1 = ix0 + 1,  iy1 = iy0 + 1;

        const float vx0 = (ix0 >= 0 && ix0 < W) ? 1.f : 0.f;
        const float vx1 = (ix1 >= 0 && ix1 < W) ? 1.f : 0.f;
        const float vy0 = (iy0 >= 0 && iy0 < H) ? 1.f : 0.f;
        const float vy1 = (iy1 >= 0 && iy1 < H) ? 1.f : 0.f;
        const int cx0 = min(max(ix0, 0), W - 1);
        const int cx1 = min(max(ix1, 0), W - 1);
        const int cy0 = min(max(iy0, 0), H - 1);
        const int cy1 = min(max(iy1, 0), H - 1);
        const int base = n * LenIn + start;

        sIdx[t][0] = base + cy0 * W + cx0;
        sIdx[t][1] = base + cy0 * W + cx1;
        sIdx[t][2] = base + cy1 * W + cx0;
        sIdx[t][3] = base + cy1 * W + cx1;
        sW[t][0] = (1.f - lx) * (1.f - ly) * vx0 * vy0;
        sW[t][1] = lx * (1.f - ly) * vx1 * vy0;
        sW[t][2] = (1.f - lx) * ly * vx0 * vy1;
        sW[t][3] = lx * ly * vx1 * vy1;

        sLt[t] = logit_top[(size_t)bid * 128 + t];
        sLb[t] = logit_bot[(size_t)bid * 128 + t];
    }
    __syncthreads();

    if (t < 16) {
        const int h = t & 7;
        const float* L = (t < 8) ? sLt : sLb;
        float* Aout    = (t < 8) ? sAt : sAb;
        float m = -1e30f;
        for (int j = 0; j < 16; ++j) m = fmaxf(m, L[h * 16 + j]);
        float e[16], s = 0.f;
        for (int j = 0; j < 16; ++j) { e[j] = expf(L[h * 16 + j] - m); s += e[j]; }
        const float inv = 1.f / s;
        for (int j = 0; j < 16; ++j) Aout[h * 16 + j] = e[j] * inv;
    }
    __syncthreads();

    const int h  = t / 24;
    const int c2 = (t % 24) * 2;
    const int colbase = h * HD + c2;

    float atx = 0.f, aty = 0.f, abx = 0.f, aby = 0.f;
    for (int lp = 0; lp < 16; ++lp) {
        const int e = h * 16 + lp;
        const float wat = sAt[e];
        const float wab = sAb[e];
        float ptx = 0.f, pty = 0.f, pbx = 0.f, pby = 0.f;
#pragma unroll
        for (int k = 0; k < 4; ++k) {
            const float w = sW[e][k];
            const size_t idx = (size_t)sIdx[e][k] * DM + colbase;
            const unsigned ut = *(const unsigned*)&val_top[idx];
            const unsigned ub = *(const unsigned*)&val_bot[idx];
            ptx = fmaf(w, bflo(ut), ptx);
            pty = fmaf(w, bfhi(ut), pty);
            pbx = fmaf(w, bflo(ub), pbx);
            pby = fmaf(w, bfhi(ub), pby);
        }
        atx = fmaf(wat, ptx, atx);
        aty = fmaf(wat, pty, aty);
        abx = fmaf(wab, pbx, abx);
        aby = fmaf(wab, pby, aby);
    }
    float2 ot; ot.x = atx; ot.y = aty;
    float2 ob; ob.x = abx; ob.y = aby;
    *(float2*)&core_top[(size_t)bid * DM + colbase] = ot;
    *(float2*)&core_bot[(size_t)bid * DM + colbase] = ob;
}

// =====================================================================
// Host launcher
// =====================================================================
extern "C" void kernel_launch(void* const* d_in, const int* in_sizes, int n_in,
                              void* d_out, int out_size, void* d_ws, size_t ws_size,
                              hipStream_t stream) {
    const float* query   = (const float*)d_in[0];
    const float* refpts  = (const float*)d_in[1];
    const float* flat    = (const float*)d_in[2];
    const int*   ss      = (const int*)d_in[3];
    const int*   lsi     = (const int*)d_in[4];
    const float* W_off   = (const float*)d_in[5];
    const float* b_off   = (const float*)d_in[6];
    const float* W_attn  = (const float*)d_in[7];
    const float* b_attn  = (const float*)d_in[8];
    const float* W_val   = (const float*)d_in[9];
    const float* b_val   = (const float*)d_in[10];
    const float* W_out   = (const float*)d_in[11];
    const float* b_out   = (const float*)d_in[12];
    const float* W_attn_zd = (const float*)d_in[13];
    const float* b_attn_zd = (const float*)d_in[14];
    const float* W_val_zd  = (const float*)d_in[15];
    const float* b_val_zd  = (const float*)d_in[16];
    const float* W_out_zd  = (const float*)d_in[17];
    const float* b_out_zd  = (const float*)d_in[18];

    const int Lq    = in_sizes[0] / (2 * DM);   // 5440
    const int LenIn = in_sizes[2] / (2 * DM);   // 5440
    const int M  = 2 * Lq;      // 10880
    const int Mv = 2 * LenIn;   // 10880

    float* out = (float*)d_out;

    // workspace layout
    float* ws      = (float*)d_ws;
    float* off_buf = ws;                               // M*256 f32
    float* lt      = off_buf + (size_t)M * 256;        // M*128 f32
    float* lb      = lt + (size_t)M * 128;             // M*128 f32
    float* ct      = lb + (size_t)M * 128;             // M*384 f32
    float* cb      = ct + (size_t)M * 384;             // M*384 f32
    __hip_bfloat16* vt  = (__hip_bfloat16*)(cb + (size_t)M * 384);  // Mv*384 bf16
    __hip_bfloat16* vb  = vt + (size_t)Mv * 384;                    // Mv*384 bf16
    __hip_bfloat16* wtb = vb + (size_t)Mv * 384;                    // 475136 bf16

    // transposed bf16 weights
    WtAll wd;
    const float* srcs[6] = {W_attn, W_attn_zd, W_val, W_val_zd, W_out, W_out_zd};
    const int Ks[6] = {256, 384, 256, 384, 384, 384};
    const int Ns[6] = {128, 128, 384, 384, 256, 128};
    __hip_bfloat16* dsts[6];
    int off = 0;
    for (int i = 0; i < 6; ++i) {
        wd.src[i] = srcs[i]; wd.K[i] = Ks[i]; wd.N[i] = Ns[i];
        wd.off[i] = off;
        dsts[i] = wtb + off;
        wd.dst[i] = dsts[i];
        off += Ks[i] * Ns[i];
    }
    wd.off[6] = off;

    const dim3 blk(256);
    const int mg = M / 128;   // 85

    // P0: weight transpose+convert
    wt_kernel<<<dim3((off + 255) / 256), blk, 0, stream>>>(wd);

    // P1 (fp32, geometry-sensitive): off = query[:,:256] @ W_off + b_off
    gemm_bias_kernel<<<dim3(M / 64, 4), blk, 0, stream>>>(
        query, DM, W_off, 256, b_off, off_buf, 256, U2);

    // P2: logits_top (M,128), K=256
    gemm_mfma_kernel<float><<<dim3(mg, 1), blk, 0, stream>>>(
        query, DM, dsts[0], 256, b_attn, lt, 128, 256);
    // P3: logits_bot (M,128), K=384
    gemm_mfma_kernel<float><<<dim3(mg, 1), blk, 0, stream>>>(
        query, DM, dsts[1], 384, b_attn_zd, lb, 128, 384);
    // P4: val_top (Mv,384) bf16, K=256
    gemm_mfma_kernel<__hip_bfloat16><<<dim3(mg, 3), blk, 0, stream>>>(
        flat, DM, dsts[2], 256, b_val, vt, 384, 256);
    // P5: val_bot (Mv,384) bf16, K=384
    gemm_mfma_kernel<__hip_bfloat16><<<dim3(mg, 3), blk, 0, stream>>>(
        flat, DM, dsts[3], 384, b_val_zd, vb, 384, 384);

    // P6: fused sampler
    sampler_kernel<<<dim3(M), dim3(192), 0, stream>>>(
        off_buf, lt, lb, refpts, ss, lsi, vt, vb, ct, cb, Lq, LenIn);

    // P7: out[:, :256] = ct @ W_out + b_out, K=384
    gemm_mfma_kernel<float><<<dim3(mg, 2), blk, 0, stream>>>(
        ct, DM, dsts[4], 384, b_out, out, DM, 384);
    // P8: out[:, 256:] = cb @ W_out_zd + b_out_zd, K=384
    gemm_mfma_kernel<float><<<dim3(mg, 1), blk, 0, stream>>>(
        cb, DM, dsts[5], 384, b_out_zd, out + U2, DM, 384);
}

// Round 3
// 291.890 us; speedup vs baseline: 1.5444x; 1.0400x over previous
//
#include <hip/hip_runtime.h>
#include <hip/hip_bf16.h>
#include <math.h>

// Problem constants: N=2, D=384, 2U=256, nH=8, hd=48, nL=4, nP=4
#define DM   384
#define U2   256
#define HD   48

typedef __attribute__((ext_vector_type(8))) short short8;   // 8 bf16 = 4 VGPR
typedef __attribute__((ext_vector_type(4))) float floatx4;  // MFMA acc

static __device__ __forceinline__ unsigned short f2bfbits(float f) {
    __hip_bfloat16 h = __float2bfloat16(f);
    return *reinterpret_cast<unsigned short*>(&h);
}
static __device__ __forceinline__ unsigned pack2(float x, float y) {
    return (unsigned)f2bfbits(x) | ((unsigned)f2bfbits(y) << 16);
}
static __device__ __forceinline__ float bflo(unsigned u) { return __uint_as_float(u << 16); }
static __device__ __forceinline__ float bfhi(unsigned u) { return __uint_as_float(u & 0xffff0000u); }

// =====================================================================
// Weight prep: 6 plain transposed bf16 weights + W_off split (hi/lo).
// =====================================================================
struct WtAll {
    const float* src[6];
    __hip_bfloat16* dst[6];
    int K[6], N[6], off[7];
    const float* woff;          // (256,256) row-major
    __hip_bfloat16 *whi, *wlo;  // (256,256) transposed
    int total;                  // off[6] + 65536
};
__global__ __launch_bounds__(256) void wt_kernel(WtAll d) {
    const int idx = blockIdx.x * 256 + threadIdx.x;
    if (idx >= d.total) return;
    if (idx < d.off[6]) {
        int s = 0;
#pragma unroll
        for (int i = 1; i < 6; ++i) if (idx >= d.off[i]) s = i;
        const int r = idx - d.off[s];
        const int k = r / d.N[s], n = r - k * d.N[s];
        d.dst[s][(size_t)n * d.K[s] + k] = __float2bfloat16(d.src[s][r]);
    } else {
        const int r = idx - d.off[6];
        const int k = r >> 8, n = r & 255;
        const float w = d.woff[r];
        const __hip_bfloat16 hi = __float2bfloat16(w);
        const float lo = w - __bfloat162float(hi);
        d.whi[n * 256 + k] = hi;
        d.wlo[n * 256 + k] = __float2bfloat16(lo);
    }
}

// =====================================================================
// Segmented bf16 MFMA GEMM: two segments selected by blockIdx.y.
// C(M x N) = A_f32(M x K) @ Wt_bf16(N x K)^T + bias, 128x128 tile, BK=32.
// =====================================================================
struct SegParams {
    const float* A[2]; int lda[2];
    const __hip_bfloat16* Bt[2]; int ldbt[2];
    const float* bias[2];
    void* C[2]; int ldc[2]; int obf[2];   // obf: 1 = bf16 output
    int K[2];
    int ysplit;                           // by < ysplit -> segment 0
};
__global__ __launch_bounds__(256) void gemm_seg_kernel(SegParams p) {
    __shared__ __hip_bfloat16 As[128 * 40];
    __shared__ __hip_bfloat16 Bs[128 * 40];

    const int s  = (blockIdx.y < (unsigned)p.ysplit) ? 0 : 1;
    const int by = blockIdx.y - (s ? p.ysplit : 0);
    const float* A = p.A[s];
    const int lda = p.lda[s];
    const __hip_bfloat16* Bt = p.Bt[s];
    const int ldbt = p.ldbt[s];
    const int K = p.K[s];

    const int t    = threadIdx.x;
    const int bm   = blockIdx.x * 128;
    const int bn   = by * 128;
    const int w    = t >> 6, lane = t & 63;
    const int wm   = (w >> 1) * 64, wn = (w & 1) * 64;
    const int quad = lane >> 4, lm = lane & 15;

    const int am = t >> 3, ak = (t & 7) * 4;
    const int bn_ = t & 127, bk0 = (t >> 7) * 8;

    floatx4 acc[4][4] = {};

    for (int k0 = 0; k0 < K; k0 += 32) {
#pragma unroll
        for (int i = 0; i < 4; ++i) {
            const int m = am + 32 * i;
            const float4 av = *(const float4*)&A[(size_t)(bm + m) * lda + k0 + ak];
            uint2 pk; pk.x = pack2(av.x, av.y); pk.y = pack2(av.z, av.w);
            *(uint2*)&As[m * 40 + ak] = pk;
        }
#pragma unroll
        for (int q = 0; q < 2; ++q) {
            const int k = bk0 + 16 * q;
            *(short8*)&Bs[bn_ * 40 + k] =
                *(const short8*)&Bt[(size_t)(bn + bn_) * ldbt + k0 + k];
        }
        __syncthreads();

        short8 af[4], bf[4];
#pragma unroll
        for (int i = 0; i < 4; ++i)
            af[i] = *(const short8*)&As[(wm + i * 16 + lm) * 40 + quad * 8];
#pragma unroll
        for (int j = 0; j < 4; ++j)
            bf[j] = *(const short8*)&Bs[(wn + j * 16 + lm) * 40 + quad * 8];
#pragma unroll
        for (int i = 0; i < 4; ++i)
#pragma unroll
            for (int j = 0; j < 4; ++j)
                acc[i][j] = __builtin_amdgcn_mfma_f32_16x16x32_bf16(
                    af[i], bf[j], acc[i][j], 0, 0, 0);
        __syncthreads();
    }

    const float* bias = p.bias[s];
    const int ldc = p.ldc[s];
#pragma unroll
    for (int i = 0; i < 4; ++i) {
#pragma unroll
        for (int reg = 0; reg < 4; ++reg) {
            const int row = bm + wm + i * 16 + quad * 4 + reg;
#pragma unroll
            for (int j = 0; j < 4; ++j) {
                const int col = bn + wn + j * 16 + lm;
                const float v = acc[i][j][reg] + bias[col];
                if (p.obf[s]) {
                    ((__hip_bfloat16*)p.C[s])[(size_t)row * ldc + col] = __float2bfloat16(v);
                } else {
                    ((float*)p.C[s])[(size_t)row * ldc + col] = v;
                }
            }
        }
    }
}

// =====================================================================
// Split-bf16 MFMA GEMM for the offset projection (fp32-accurate):
// C = A @ W + b with A=Ahi+Alo, W=Whi+Wlo; acc = AhiWhi + AhiWlo + AloWhi.
// =====================================================================
__global__ __launch_bounds__(256) void gemm_off_kernel(
    const float* __restrict__ A, int lda,
    const __hip_bfloat16* __restrict__ Bhi,
    const __hip_bfloat16* __restrict__ Blo, int ldbt,
    const float* __restrict__ bias,
    float* __restrict__ C, int ldc, int K)
{
    __shared__ __hip_bfloat16 Ah[128 * 40];
    __shared__ __hip_bfloat16 Al[128 * 40];
    __shared__ __hip_bfloat16 Bh[128 * 40];
    __shared__ __hip_bfloat16 Bl[128 * 40];

    const int t    = threadIdx.x;
    const int bm   = blockIdx.x * 128;
    const int bn   = blockIdx.y * 128;
    const int w    = t >> 6, lane = t & 63;
    const int wm   = (w >> 1) * 64, wn = (w & 1) * 64;
    const int quad = lane >> 4, lm = lane & 15;

    const int am = t >> 3, ak = (t & 7) * 4;
    const int bn_ = t & 127, bk0 = (t >> 7) * 8;

    floatx4 acc[4][4] = {};

    for (int k0 = 0; k0 < K; k0 += 32) {
#pragma unroll
        for (int i = 0; i < 4; ++i) {
            const int m = am + 32 * i;
            const float4 av = *(const float4*)&A[(size_t)(bm + m) * lda + k0 + ak];
            float hx = __bfloat162float(__float2bfloat16(av.x));
            float hy = __bfloat162float(__float2bfloat16(av.y));
            float hz = __bfloat162float(__float2bfloat16(av.z));
            float hw = __bfloat162float(__float2bfloat16(av.w));
            uint2 ph; ph.x = pack2(hx, hy); ph.y = pack2(hz, hw);
            uint2 pl; pl.x = pack2(av.x - hx, av.y - hy); pl.y = pack2(av.z - hz, av.w - hw);
            *(uint2*)&Ah[m * 40 + ak] = ph;
            *(uint2*)&Al[m * 40 + ak] = pl;
        }
#pragma unroll
        for (int q = 0; q < 2; ++q) {
            const int k = bk0 + 16 * q;
            *(short8*)&Bh[bn_ * 40 + k] =
                *(const short8*)&Bhi[(size_t)(bn + bn_) * ldbt + k0 + k];
            *(short8*)&Bl[bn_ * 40 + k] =
                *(const short8*)&Blo[(size_t)(bn + bn_) * ldbt + k0 + k];
        }
        __syncthreads();

        short8 ah[4], al[4], bh[4], bl[4];
#pragma unroll
        for (int i = 0; i < 4; ++i) {
            ah[i] = *(const short8*)&Ah[(wm + i * 16 + lm) * 40 + quad * 8];
            al[i] = *(const short8*)&Al[(wm + i * 16 + lm) * 40 + quad * 8];
        }
#pragma unroll
        for (int j = 0; j < 4; ++j) {
            bh[j] = *(const short8*)&Bh[(wn + j * 16 + lm) * 40 + quad * 8];
            bl[j] = *(const short8*)&Bl[(wn + j * 16 + lm) * 40 + quad * 8];
        }
#pragma unroll
        for (int i = 0; i < 4; ++i)
#pragma unroll
            for (int j = 0; j < 4; ++j) {
                acc[i][j] = __builtin_amdgcn_mfma_f32_16x16x32_bf16(ah[i], bh[j], acc[i][j], 0, 0, 0);
                acc[i][j] = __builtin_amdgcn_mfma_f32_16x16x32_bf16(ah[i], bl[j], acc[i][j], 0, 0, 0);
                acc[i][j] = __builtin_amdgcn_mfma_f32_16x16x32_bf16(al[i], bh[j], acc[i][j], 0, 0, 0);
            }
        __syncthreads();
    }

#pragma unroll
    for (int i = 0; i < 4; ++i)
#pragma unroll
        for (int reg = 0; reg < 4; ++reg) {
            const int row = bm + wm + i * 16 + quad * 4 + reg;
#pragma unroll
            for (int j = 0; j < 4; ++j) {
                const int col = bn + wn + j * 16 + lm;
                C[(size_t)row * ldc + col] = acc[i][j][reg] + bias[col];
            }
        }
}

// =====================================================================
// Fused sampler. Phase 3: t<96 = top branch, t>=96 = bot branch;
// each thread owns 4 channels of one head -> uint2 (4x bf16) gathers.
// LDS swizzle SWIDX/SAIDX spreads the 6 distinct e-per-wave over 4 banks.
// =====================================================================
#define SWIDX(e,k) ((e) * 5 + (((e) >> 4) << 3) + (k))
#define SAIDX(e)   ((e) + (((e) >> 4) << 3))

__global__ __launch_bounds__(192) void sampler_kernel(
    const float* __restrict__ off_buf,    // (M, 256) fp32
    const float* __restrict__ logit_top,  // (M, 128)
    const float* __restrict__ logit_bot,  // (M, 128)
    const float* __restrict__ ref_pts,    // (M, 4, 2)
    const int*   __restrict__ ss,         // (4,2) [H,W]
    const int*   __restrict__ lsi,        // (4,)
    const __hip_bfloat16* __restrict__ val_top,  // (Mv, 384) bf16
    const __hip_bfloat16* __restrict__ val_bot,  // (Mv, 384) bf16
    float* __restrict__ core_top,         // (M, 384)
    float* __restrict__ core_bot,         // (M, 384)
    int Lq, int LenIn)
{
    __shared__ int   sOffB[704];   // byte offsets idx*768, swizzled
    __shared__ float sW[704];
    __shared__ float sLt[128], sLb[128];
    __shared__ float sAt[192], sAb[192];

    const int bid = blockIdx.x;
    const int n   = bid / Lq;
    const int t   = threadIdx.x;

    if (t < 128) {
        const int l = (t >> 2) & 3;
        const float2 offv = *(const float2*)&off_buf[(size_t)bid * 256 + 2 * t];
        const float rx = ref_pts[(size_t)(bid * 4 + l) * 2 + 0];
        const float ry = ref_pts[(size_t)(bid * 4 + l) * 2 + 1];
        const int H = ss[2 * l], W = ss[2 * l + 1];
        const int start = lsi[l];

        const float x = (rx + offv.x / (float)W) * (float)W - 0.5f;
        const float y = (ry + offv.y / (float)H) * (float)H - 0.5f;
        const float x0f = floorf(x), y0f = floorf(y);
        const float lx = x - x0f, ly = y - y0f;
        const int ix0 = (int)x0f, iy0 = (int)y0f;
        const int ix1 = ix0 + 1,  iy1 = iy0 + 1;

        const float vx0 = (ix0 >= 0 && ix0 < W) ? 1.f : 0.f;
        const float vx1 = (ix1 >= 0 && ix1 < W) ? 1.f : 0.f;
        const float vy0 = (iy0 >= 0 && iy0 < H) ? 1.f : 0.f;
        const float vy1 = (iy1 >= 0 && iy1 < H) ? 1.f : 0.f;
        const int cx0 = min(max(ix0, 0), W - 1);
        const int cx1 = min(max(ix1, 0), W - 1);
        const int cy0 = min(max(iy0, 0), H - 1);
        const int cy1 = min(max(iy1, 0), H - 1);
        const int base = n * LenIn + start;

        sOffB[SWIDX(t,0)] = (base + cy0 * W + cx0) * (DM * 2);
        sOffB[SWIDX(t,1)] = (base + cy0 * W + cx1) * (DM * 2);
        sOffB[SWIDX(t,2)] = (base + cy1 * W + cx0) * (DM * 2);
        sOffB[SWIDX(t,3)] = (base + cy1 * W + cx1) * (DM * 2);
        sW[SWIDX(t,0)] = (1.f - lx) * (1.f - ly) * vx0 * vy0;
        sW[SWIDX(t,1)] = lx * (1.f - ly) * vx1 * vy0;
        sW[SWIDX(t,2)] = (1.f - lx) * ly * vx0 * vy1;
        sW[SWIDX(t,3)] = lx * ly * vx1 * vy1;

        sLt[t] = logit_top[(size_t)bid * 128 + t];
        sLb[t] = logit_bot[(size_t)bid * 128 + t];
    }
    __syncthreads();

    if (t < 16) {
        const int h = t & 7;
        const float* L = (t < 8) ? sLt : sLb;
        float* Aout    = (t < 8) ? sAt : sAb;
        float m = -1e30f;
        for (int j = 0; j < 16; ++j) m = fmaxf(m, L[h * 16 + j]);
        float e[16], sum = 0.f;
        for (int j = 0; j < 16; ++j) { e[j] = expf(L[h * 16 + j] - m); sum += e[j]; }
        const float inv = 1.f / sum;
        for (int j = 0; j < 16; ++j) Aout[SAIDX(h * 16 + j)] = e[j] * inv;
    }
    __syncthreads();

    // phase 3
    const int br = t / 96;          // 0 = top, 1 = bot
    const int u  = t - br * 96;
    const int h  = u / 12;
    const int c4 = (u - h * 12) * 4;
    const int colbase = h * HD + c4;

    const float* sA = br ? sAb : sAt;
    const char* vbase = (const char*)(br ? val_bot : val_top) + colbase * 2;

    float a0 = 0.f, a1 = 0.f, a2 = 0.f, a3 = 0.f;
    for (int lp = 0; lp < 16; ++lp) {
        const int e = h * 16 + lp;
        const float wat = sA[SAIDX(e)];
        float p0 = 0.f, p1 = 0.f, p2 = 0.f, p3 = 0.f;
#pragma unroll
        for (int k = 0; k < 4; ++k) {
            const float w = sW[SWIDX(e,k)];
            const uint2 v = *(const uint2*)(vbase + sOffB[SWIDX(e,k)]);
            p0 = fmaf(w, bflo(v.x), p0);
            p1 = fmaf(w, bfhi(v.x), p1);
            p2 = fmaf(w, bflo(v.y), p2);
            p3 = fmaf(w, bfhi(v.y), p3);
        }
        a0 = fmaf(wat, p0, a0);
        a1 = fmaf(wat, p1, a1);
        a2 = fmaf(wat, p2, a2);
        a3 = fmaf(wat, p3, a3);
    }
    float4 o; o.x = a0; o.y = a1; o.z = a2; o.w = a3;
    float* dst = br ? core_bot : core_top;
    *(float4*)&dst[(size_t)bid * DM + colbase] = o;
}

// =====================================================================
// Host launcher
// =====================================================================
extern "C" void kernel_launch(void* const* d_in, const int* in_sizes, int n_in,
                              void* d_out, int out_size, void* d_ws, size_t ws_size,
                              hipStream_t stream) {
    const float* query   = (const float*)d_in[0];
    const float* refpts  = (const float*)d_in[1];
    const float* flat    = (const float*)d_in[2];
    const int*   ss      = (const int*)d_in[3];
    const int*   lsi     = (const int*)d_in[4];
    const float* W_off   = (const float*)d_in[5];
    const float* b_off   = (const float*)d_in[6];
    const float* W_attn  = (const float*)d_in[7];
    const float* b_attn  = (const float*)d_in[8];
    const float* W_val   = (const float*)d_in[9];
    const float* b_val   = (const float*)d_in[10];
    const float* W_out   = (const float*)d_in[11];
    const float* b_out   = (const float*)d_in[12];
    const float* W_attn_zd = (const float*)d_in[13];
    const float* b_attn_zd = (const float*)d_in[14];
    const float* W_val_zd  = (const float*)d_in[15];
    const float* b_val_zd  = (const float*)d_in[16];
    const float* W_out_zd  = (const float*)d_in[17];
    const float* b_out_zd  = (const float*)d_in[18];

    const int Lq    = in_sizes[0] / (2 * DM);   // 5440
    const int LenIn = in_sizes[2] / (2 * DM);   // 5440
    const int M  = 2 * Lq;      // 10880
    const int Mv = 2 * LenIn;   // 10880

    float* out = (float*)d_out;

    // workspace layout
    float* ws      = (float*)d_ws;
    float* off_buf = ws;                               // M*256 f32
    float* lt      = off_buf + (size_t)M * 256;        // M*128 f32
    float* lb      = lt + (size_t)M * 128;             // M*128 f32
    float* ct      = lb + (size_t)M * 128;             // M*384 f32
    float* cb      = ct + (size_t)M * 384;             // M*384 f32
    __hip_bfloat16* vt  = (__hip_bfloat16*)(cb + (size_t)M * 384);  // Mv*384
    __hip_bfloat16* vb  = vt + (size_t)Mv * 384;                    // Mv*384
    __hip_bfloat16* wtb = vb + (size_t)Mv * 384;

    WtAll wd;
    const float* srcs[6] = {W_attn, W_attn_zd, W_val, W_val_zd, W_out, W_out_zd};
    const int Ks[6] = {256, 384, 256, 384, 384, 384};
    const int Ns[6] = {128, 128, 384, 384, 256, 128};
    __hip_bfloat16* dsts[6];
    int off = 0;
    for (int i = 0; i < 6; ++i) {
        wd.src[i] = srcs[i]; wd.K[i] = Ks[i]; wd.N[i] = Ns[i];
        wd.off[i] = off;
        dsts[i] = wtb + off;
        wd.dst[i] = dsts[i];
        off += Ks[i] * Ns[i];
    }
    wd.off[6] = off;
    __hip_bfloat16* whi = wtb + off;
    __hip_bfloat16* wlo = whi + 256 * 256;
    wd.woff = W_off; wd.whi = whi; wd.wlo = wlo;
    wd.total = off + 256 * 256;

    const dim3 blk(256);
    const int mg = M / 128;   // 85

    // P0: weight prep
    wt_kernel<<<dim3((wd.total + 255) / 256), blk, 0, stream>>>(wd);

    // P1: offsets via split-bf16 MFMA (fp32-accurate), grid (85,2)
    gemm_off_kernel<<<dim3(mg, 2), blk, 0, stream>>>(
        query, DM, whi, wlo, 256, b_off, off_buf, 256, U2);

    // P23: both logit GEMMs in one launch, grid (85,2)
    {
        SegParams p;
        p.A[0] = query; p.lda[0] = DM; p.Bt[0] = dsts[0]; p.ldbt[0] = 256;
        p.bias[0] = b_attn; p.C[0] = lt; p.ldc[0] = 128; p.obf[0] = 0; p.K[0] = 256;
        p.A[1] = query; p.lda[1] = DM; p.Bt[1] = dsts[1]; p.ldbt[1] = 384;
        p.bias[1] = b_attn_zd; p.C[1] = lb; p.ldc[1] = 128; p.obf[1] = 0; p.K[1] = 384;
        p.ysplit = 1;
        gemm_seg_kernel<<<dim3(mg, 2), blk, 0, stream>>>(p);
    }
    // P45: both value GEMMs (bf16 out), grid (85,6)
    {
        SegParams p;
        p.A[0] = flat; p.lda[0] = DM; p.Bt[0] = dsts[2]; p.ldbt[0] = 256;
        p.bias[0] = b_val; p.C[0] = vt; p.ldc[0] = 384; p.obf[0] = 1; p.K[0] = 256;
        p.A[1] = flat; p.lda[1] = DM; p.Bt[1] = dsts[3]; p.ldbt[1] = 384;
        p.bias[1] = b_val_zd; p.C[1] = vb; p.ldc[1] = 384; p.obf[1] = 1; p.K[1] = 384;
        p.ysplit = 3;
        gemm_seg_kernel<<<dim3(mg, 6), blk, 0, stream>>>(p);
    }

    // P6: fused sampler
    sampler_kernel<<<dim3(M), dim3(192), 0, stream>>>(
        off_buf, lt, lb, refpts, ss, lsi, vt, vb, ct, cb, Lq, LenIn);

    // P78: both output GEMMs into d_out, grid (85,3)
    {
        SegParams p;
        p.A[0] = ct; p.lda[0] = DM; p.Bt[0] = dsts[4]; p.ldbt[0] = 384;
        p.bias[0] = b_out; p.C[0] = out; p.ldc[0] = DM; p.obf[0] = 0; p.K[0] = 384;
        p.A[1] = cb; p.lda[1] = DM; p.Bt[1] = dsts[5]; p.ldbt[1] = 384;
        p.bias[1] = b_out_zd; p.C[1] = out + U2; p.ldc[1] = DM; p.obf[1] = 0; p.K[1] = 384;
        p.ysplit = 2;
        gemm_seg_kernel<<<dim3(mg, 3), blk, 0, stream>>>(p);
    }
}

// Round 4
// 274.555 us; speedup vs baseline: 1.6419x; 1.0631x over previous
//
#include <hip/hip_runtime.h>
#include <hip/hip_bf16.h>
#include <math.h>

// Problem constants: N=2, D=384, 2U=256, nH=8, hd=48, nL=4, nP=4
#define DM   384
#define U2   256
#define HD   48

typedef __attribute__((ext_vector_type(8))) short short8;   // 8 bf16 = 4 VGPR
typedef __attribute__((ext_vector_type(4))) float floatx4;  // MFMA acc

static __device__ __forceinline__ unsigned short f2bfbits(float f) {
    __hip_bfloat16 h = __float2bfloat16(f);
    return *reinterpret_cast<unsigned short*>(&h);
}
static __device__ __forceinline__ unsigned pack2(float x, float y) {
    return (unsigned)f2bfbits(x) | ((unsigned)f2bfbits(y) << 16);
}
static __device__ __forceinline__ float bflo(unsigned u) { return __uint_as_float(u << 16); }
static __device__ __forceinline__ float bfhi(unsigned u) { return __uint_as_float(u & 0xffff0000u); }

// =====================================================================
// Prep: query->bf16 (+hi/lo split for offset path), flat->bf16,
// 6 weight transposes, W_off hi/lo transposed split. One launch.
// =====================================================================
struct PrepParams {
    const float* q; const float* f;
    __hip_bfloat16 *q_bf, *q_lo, *f_bf;
    const float* wsrc[6]; __hip_bfloat16* wdst[6];
    int K[6], N[6], off[7];
    const float* woff; __hip_bfloat16 *whi, *wlo;
    int nQ4, nF4, total;
};
__global__ __launch_bounds__(256) void prep_kernel(PrepParams d) {
    const int idx = blockIdx.x * 256 + threadIdx.x;
    if (idx >= d.total) return;
    if (idx < d.nQ4) {
        const int i4 = idx * 4;
        const float4 v = *(const float4*)&d.q[i4];
        uint2 pk; pk.x = pack2(v.x, v.y); pk.y = pack2(v.z, v.w);
        *(uint2*)&d.q_bf[i4] = pk;
        const int row = i4 / DM, col = i4 - row * DM;
        if (col < U2) {
            const float hx = bflo(pk.x), hy = bfhi(pk.x);
            const float hz = bflo(pk.y), hw = bfhi(pk.y);
            uint2 pl; pl.x = pack2(v.x - hx, v.y - hy); pl.y = pack2(v.z - hz, v.w - hw);
            *(uint2*)&d.q_lo[row * U2 + col] = pl;
        }
        return;
    }
    if (idx < d.nQ4 + d.nF4) {
        const int i4 = (idx - d.nQ4) * 4;
        const float4 v = *(const float4*)&d.f[i4];
        uint2 pk; pk.x = pack2(v.x, v.y); pk.y = pack2(v.z, v.w);
        *(uint2*)&d.f_bf[i4] = pk;
        return;
    }
    const int iw = idx - d.nQ4 - d.nF4;
    if (iw < d.off[6]) {
        int s = 0;
#pragma unroll
        for (int i = 1; i < 6; ++i) if (iw >= d.off[i]) s = i;
        const int r = iw - d.off[s];
        const int k = r / d.N[s], n = r - k * d.N[s];
        d.wdst[s][(size_t)n * d.K[s] + k] = __float2bfloat16(d.wsrc[s][r]);
    } else {
        const int r = iw - d.off[6];          // < 65536
        const int k = r >> 8, n = r & 255;
        const float w = d.woff[r];
        const __hip_bfloat16 hi = __float2bfloat16(w);
        const float lo = w - __bfloat162float(hi);
        d.whi[n * 256 + k] = hi;
        d.wlo[n * 256 + k] = __float2bfloat16(lo);
    }
}

// =====================================================================
// Multi-segment bf16 MFMA GEMM. Segment picked by blockIdx.y range.
// C(M x N) = A_bf16(M x K) @ Bt_bf16(N x K)^T + bias. 128x128 tile, BK=32.
// flags: bit0 = bf16 output; bit1 = split (A=Ah+Al, B=Bh+Bl, 3 MFMAs).
// =====================================================================
struct Seg {
    const __hip_bfloat16* A;  const __hip_bfloat16* Alo;
    int lda, ldalo;
    const __hip_bfloat16* Bt; const __hip_bfloat16* Btlo;
    int ldbt;
    const float* bias; void* C; int ldc; int K; int flags;
};
struct SegParams { Seg seg[5]; int ystart[5]; int nseg; };

__global__ __launch_bounds__(256) void gemm_seg_kernel(SegParams p) {
    __shared__ __hip_bfloat16 Ah[128 * 40];
    __shared__ __hip_bfloat16 Bh[128 * 40];
    __shared__ __hip_bfloat16 Al[128 * 40];
    __shared__ __hip_bfloat16 Bl[128 * 40];

    int s = 0;
    for (int i = 1; i < p.nseg; ++i) if ((int)blockIdx.y >= p.ystart[i]) s = i;
    const Seg sg = p.seg[s];
    const int by = blockIdx.y - p.ystart[s];
    const bool split = (sg.flags & 2) != 0;

    const int t    = threadIdx.x;
    const int bm   = blockIdx.x * 128;
    const int bn   = by * 128;
    const int w    = t >> 6, lane = t & 63;
    const int wm   = (w >> 1) * 64, wn = (w & 1) * 64;
    const int quad = lane >> 4, lm = lane & 15;

    // staging: chunk c = t + 256*i; row = c>>2, kc = (c&3)*8 (short8)
    const int r0 = t >> 2, kc = (t & 3) * 8;

    floatx4 acc[4][4] = {};

    for (int k0 = 0; k0 < sg.K; k0 += 32) {
#pragma unroll
        for (int i = 0; i < 2; ++i) {
            const int row = r0 + 64 * i;
            *(short8*)&Ah[row * 40 + kc] =
                *(const short8*)&sg.A[(size_t)(bm + row) * sg.lda + k0 + kc];
            *(short8*)&Bh[row * 40 + kc] =
                *(const short8*)&sg.Bt[(size_t)(bn + row) * sg.ldbt + k0 + kc];
        }
        if (split) {
#pragma unroll
            for (int i = 0; i < 2; ++i) {
                const int row = r0 + 64 * i;
                *(short8*)&Al[row * 40 + kc] =
                    *(const short8*)&sg.Alo[(size_t)(bm + row) * sg.ldalo + k0 + kc];
                *(short8*)&Bl[row * 40 + kc] =
                    *(const short8*)&sg.Btlo[(size_t)(bn + row) * sg.ldbt + k0 + kc];
            }
        }
        __syncthreads();

        short8 af[4], bf[4];
#pragma unroll
        for (int i = 0; i < 4; ++i)
            af[i] = *(const short8*)&Ah[(wm + i * 16 + lm) * 40 + quad * 8];
#pragma unroll
        for (int j = 0; j < 4; ++j)
            bf[j] = *(const short8*)&Bh[(wn + j * 16 + lm) * 40 + quad * 8];
#pragma unroll
        for (int i = 0; i < 4; ++i)
#pragma unroll
            for (int j = 0; j < 4; ++j)
                acc[i][j] = __builtin_amdgcn_mfma_f32_16x16x32_bf16(
                    af[i], bf[j], acc[i][j], 0, 0, 0);
        if (split) {
            short8 al[4], bl[4];
#pragma unroll
            for (int i = 0; i < 4; ++i)
                al[i] = *(const short8*)&Al[(wm + i * 16 + lm) * 40 + quad * 8];
#pragma unroll
            for (int j = 0; j < 4; ++j)
                bl[j] = *(const short8*)&Bl[(wn + j * 16 + lm) * 40 + quad * 8];
#pragma unroll
            for (int i = 0; i < 4; ++i)
#pragma unroll
                for (int j = 0; j < 4; ++j) {
                    acc[i][j] = __builtin_amdgcn_mfma_f32_16x16x32_bf16(
                        af[i], bl[j], acc[i][j], 0, 0, 0);
                    acc[i][j] = __builtin_amdgcn_mfma_f32_16x16x32_bf16(
                        al[i], bf[j], acc[i][j], 0, 0, 0);
                }
        }
        __syncthreads();
    }

#pragma unroll
    for (int i = 0; i < 4; ++i)
#pragma unroll
        for (int reg = 0; reg < 4; ++reg) {
            const int row = bm + wm + i * 16 + quad * 4 + reg;
#pragma unroll
            for (int j = 0; j < 4; ++j) {
                const int col = bn + wn + j * 16 + lm;
                const float v = acc[i][j][reg] + sg.bias[col];
                if (sg.flags & 1)
                    ((__hip_bfloat16*)sg.C)[(size_t)row * sg.ldc + col] = __float2bfloat16(v);
                else
                    ((float*)sg.C)[(size_t)row * sg.ldc + col] = v;
            }
        }
}

// =====================================================================
// Fused sampler. Phase 1: geometry (regs). Phase 2: dual softmax.
// Phase 2.5: premultiplied (w*attn, byteoff) float2 pairs into LDS.
// Phase 3: t<96 top / t>=96 bot; 4 channels/thread; per lp: 4 ds_read_b64
// + 4 global uint2 loads. Outputs bf16 (feed the output GEMM directly).
// =====================================================================
#define PIDX(e,k) (((e) << 2) + (k) + ((e) >> 4))

__global__ __launch_bounds__(192) void sampler_kernel(
    const float* __restrict__ off_buf,    // (M, 256) fp32
    const float* __restrict__ logit_top,  // (M, 128)
    const float* __restrict__ logit_bot,  // (M, 128)
    const float* __restrict__ ref_pts,    // (M, 4, 2)
    const int*   __restrict__ ss,         // (4,2) [H,W]
    const int*   __restrict__ lsi,        // (4,)
    const __hip_bfloat16* __restrict__ val_top,  // (Mv, 384) bf16
    const __hip_bfloat16* __restrict__ val_bot,  // (Mv, 384) bf16
    __hip_bfloat16* __restrict__ core_top,       // (M, 384) bf16
    __hip_bfloat16* __restrict__ core_bot,       // (M, 384) bf16
    int Lq, int LenIn)
{
    __shared__ float2 sP[2][520];         // (w*attn, byteoff) pairs, swizzled
    __shared__ float sLt[128], sLb[128];
    __shared__ float sAt[128], sAb[128];

    const int bid = blockIdx.x;
    const int n   = bid / Lq;
    const int t   = threadIdx.x;

    float w0, w1, w2, w3;
    int   o0, o1, o2, o3;

    if (t < 128) {
        const int l = (t >> 2) & 3;
        const float2 offv = *(const float2*)&off_buf[(size_t)bid * 256 + 2 * t];
        const float rx = ref_pts[(size_t)(bid * 4 + l) * 2 + 0];
        const float ry = ref_pts[(size_t)(bid * 4 + l) * 2 + 1];
        const int H = ss[2 * l], W = ss[2 * l + 1];
        const int start = lsi[l];

        const float x = (rx + offv.x / (float)W) * (float)W - 0.5f;
        const float y = (ry + offv.y / (float)H) * (float)H - 0.5f;
        const float x0f = floorf(x), y0f = floorf(y);
        const float lx = x - x0f, ly = y - y0f;
        const int ix0 = (int)x0f, iy0 = (int)y0f;
        const int ix1 = ix0 + 1,  iy1 = iy0 + 1;

        const float vx0 = (ix0 >= 0 && ix0 < W) ? 1.f : 0.f;
        const float vx1 = (ix1 >= 0 && ix1 < W) ? 1.f : 0.f;
        const float vy0 = (iy0 >= 0 && iy0 < H) ? 1.f : 0.f;
        const float vy1 = (iy1 >= 0 && iy1 < H) ? 1.f : 0.f;
        const int cx0 = min(max(ix0, 0), W - 1);
        const int cx1 = min(max(ix1, 0), W - 1);
        const int cy0 = min(max(iy0, 0), H - 1);
        const int cy1 = min(max(iy1, 0), H - 1);
        const int base = n * LenIn + start;

        o0 = (base + cy0 * W + cx0) * (DM * 2);
        o1 = (base + cy0 * W + cx1) * (DM * 2);
        o2 = (base + cy1 * W + cx0) * (DM * 2);
        o3 = (base + cy1 * W + cx1) * (DM * 2);
        w0 = (1.f - lx) * (1.f - ly) * vx0 * vy0;
        w1 = lx * (1.f - ly) * vx1 * vy0;
        w2 = (1.f - lx) * ly * vx0 * vy1;
        w3 = lx * ly * vx1 * vy1;

        sLt[t] = logit_top[(size_t)bid * 128 + t];
        sLb[t] = logit_bot[(size_t)bid * 128 + t];
    }
    __syncthreads();

    if (t < 16) {
        const int h = t & 7;
        const float* L = (t < 8) ? sLt : sLb;
        float* Aout    = (t < 8) ? sAt : sAb;
        float m = -1e30f;
        for (int j = 0; j < 16; ++j) m = fmaxf(m, L[h * 16 + j]);
        float e[16], sum = 0.f;
        for (int j = 0; j < 16; ++j) { e[j] = expf(L[h * 16 + j] - m); sum += e[j]; }
        const float inv = 1.f / sum;
        for (int j = 0; j < 16; ++j) Aout[h * 16 + j] = e[j] * inv;
    }
    __syncthreads();

    if (t < 128) {
        const float at = sAt[t], ab = sAb[t];
        float2 pt, pb;
        pt.x = w0 * at; pt.y = __uint_as_float((unsigned)o0);
        pb.x = w0 * ab; pb.y = pt.y;
        sP[0][PIDX(t, 0)] = pt; sP[1][PIDX(t, 0)] = pb;
        pt.x = w1 * at; pt.y = __uint_as_float((unsigned)o1);
        pb.x = w1 * ab; pb.y = pt.y;
        sP[0][PIDX(t, 1)] = pt; sP[1][PIDX(t, 1)] = pb;
        pt.x = w2 * at; pt.y = __uint_as_float((unsigned)o2);
        pb.x = w2 * ab; pb.y = pt.y;
        sP[0][PIDX(t, 2)] = pt; sP[1][PIDX(t, 2)] = pb;
        pt.x = w3 * at; pt.y = __uint_as_float((unsigned)o3);
        pb.x = w3 * ab; pb.y = pt.y;
        sP[0][PIDX(t, 3)] = pt; sP[1][PIDX(t, 3)] = pb;
    }
    __syncthreads();

    // ---- phase 3 ----
    const int br = t / 96;
    const int u  = t - br * 96;
    const int h  = u / 12;
    const int c4 = (u - h * 12) * 4;
    const int colbase = h * HD + c4;
    const unsigned colb2 = (unsigned)(colbase * 2);

    const float2* P = sP[br];
    const char* vbase = (const char*)(br ? val_bot : val_top);
    const int pbase = h * 65;       // PIDX(h*16, 0)

    float a0 = 0.f, a1 = 0.f, a2 = 0.f, a3 = 0.f;
#pragma unroll 4
    for (int lp = 0; lp < 16; ++lp) {
        const int ib = pbase + lp * 4;
#pragma unroll
        for (int k = 0; k < 4; ++k) {
            const float2 pr = P[ib + k];
            const uint2 v = *(const uint2*)(vbase + (__float_as_uint(pr.y) + colb2));
            a0 = fmaf(pr.x, bflo(v.x), a0);
            a1 = fmaf(pr.x, bfhi(v.x), a1);
            a2 = fmaf(pr.x, bflo(v.y), a2);
            a3 = fmaf(pr.x, bfhi(v.y), a3);
        }
    }
    uint2 o; o.x = pack2(a0, a1); o.y = pack2(a2, a3);
    __hip_bfloat16* dst = br ? core_bot : core_top;
    *(uint2*)&dst[(size_t)bid * DM + colbase] = o;
}

// =====================================================================
// Host launcher
// =====================================================================
extern "C" void kernel_launch(void* const* d_in, const int* in_sizes, int n_in,
                              void* d_out, int out_size, void* d_ws, size_t ws_size,
                              hipStream_t stream) {
    const float* query   = (const float*)d_in[0];
    const float* refpts  = (const float*)d_in[1];
    const float* flat    = (const float*)d_in[2];
    const int*   ss      = (const int*)d_in[3];
    const int*   lsi     = (const int*)d_in[4];
    const float* W_off   = (const float*)d_in[5];
    const float* b_off   = (const float*)d_in[6];
    const float* W_attn  = (const float*)d_in[7];
    const float* b_attn  = (const float*)d_in[8];
    const float* W_val   = (const float*)d_in[9];
    const float* b_val   = (const float*)d_in[10];
    const float* W_out   = (const float*)d_in[11];
    const float* b_out   = (const float*)d_in[12];
    const float* W_attn_zd = (const float*)d_in[13];
    const float* b_attn_zd = (const float*)d_in[14];
    const float* W_val_zd  = (const float*)d_in[15];
    const float* b_val_zd  = (const float*)d_in[16];
    const float* W_out_zd  = (const float*)d_in[17];
    const float* b_out_zd  = (const float*)d_in[18];

    const int Lq    = in_sizes[0] / (2 * DM);   // 5440
    const int LenIn = in_sizes[2] / (2 * DM);   // 5440
    const int M  = 2 * Lq;      // 10880
    const int Mv = 2 * LenIn;   // 10880

    float* out = (float*)d_out;

    // ---- workspace layout ----
    float* ws      = (float*)d_ws;
    float* off_buf = ws;                               // M*256 f32
    float* lt      = off_buf + (size_t)M * 256;        // M*128 f32
    float* lb      = lt + (size_t)M * 128;             // M*128 f32
    __hip_bfloat16* q_bf = (__hip_bfloat16*)(lb + (size_t)M * 128); // M*384
    __hip_bfloat16* q_lo = q_bf + (size_t)M * 384;     // M*256
    __hip_bfloat16* f_bf = q_lo + (size_t)M * 256;     // Mv*384
    __hip_bfloat16* vt   = f_bf + (size_t)Mv * 384;    // Mv*384
    __hip_bfloat16* vb   = vt + (size_t)Mv * 384;      // Mv*384
    __hip_bfloat16* ct   = vb + (size_t)Mv * 384;      // M*384
    __hip_bfloat16* cb   = ct + (size_t)M * 384;       // M*384
    __hip_bfloat16* wtb  = cb + (size_t)M * 384;       // weights

    // ---- prep params ----
    PrepParams pp;
    pp.q = query; pp.f = flat;
    pp.q_bf = q_bf; pp.q_lo = q_lo; pp.f_bf = f_bf;
    const float* srcs[6] = {W_attn, W_attn_zd, W_val, W_val_zd, W_out, W_out_zd};
    const int Ks[6] = {256, 384, 256, 384, 384, 384};
    const int Ns[6] = {128, 128, 384, 384, 256, 128};
    __hip_bfloat16* dsts[6];
    int off = 0;
    for (int i = 0; i < 6; ++i) {
        pp.wsrc[i] = srcs[i]; pp.K[i] = Ks[i]; pp.N[i] = Ns[i];
        pp.off[i] = off;
        dsts[i] = wtb + off;
        pp.wdst[i] = dsts[i];
        off += Ks[i] * Ns[i];
    }
    pp.off[6] = off;
    __hip_bfloat16* whi = wtb + off;
    __hip_bfloat16* wlo = whi + 256 * 256;
    pp.woff = W_off; pp.whi = whi; pp.wlo = wlo;
    pp.nQ4 = M * DM / 4;
    pp.nF4 = Mv * DM / 4;
    pp.total = pp.nQ4 + pp.nF4 + off + 256 * 256;

    const dim3 blk(256);
    const int mg = M / 128;   // 85

    prep_kernel<<<dim3((pp.total + 255) / 256), blk, 0, stream>>>(pp);

    // ---- MEGA-GEMM 1: off (split) + logits + values, grid (85, 10) ----
    {
        SegParams p;
        // seg0: off = q[:, :256] @ W_off (split), N=256 -> y 0..1
        p.seg[0] = { q_bf, q_lo, DM, U2, whi, wlo, 256,
                     b_off, off_buf, 256, 256, 2 };
        // seg1: logits_top, N=128, K=256 -> y 2
        p.seg[1] = { q_bf, nullptr, DM, 0, dsts[0], nullptr, 256,
                     b_attn, lt, 128, 256, 0 };
        // seg2: logits_bot, N=128, K=384 -> y 3
        p.seg[2] = { q_bf, nullptr, DM, 0, dsts[1], nullptr, 384,
                     b_attn_zd, lb, 128, 384, 0 };
        // seg3: val_top, N=384, K=256 -> y 4..6 (bf16 out)
        p.seg[3] = { f_bf, nullptr, DM, 0, dsts[2], nullptr, 256,
                     b_val, vt, 384, 256, 1 };
        // seg4: val_bot, N=384, K=384 -> y 7..9 (bf16 out)
        p.seg[4] = { f_bf, nullptr, DM, 0, dsts[3], nullptr, 384,
                     b_val_zd, vb, 384, 384, 1 };
        p.ystart[0] = 0; p.ystart[1] = 2; p.ystart[2] = 3;
        p.ystart[3] = 4; p.ystart[4] = 7;
        p.nseg = 5;
        gemm_seg_kernel<<<dim3(mg, 10), blk, 0, stream>>>(p);
    }

    // ---- sampler ----
    sampler_kernel<<<dim3(M), dim3(192), 0, stream>>>(
        off_buf, lt, lb, refpts, ss, lsi, vt, vb, ct, cb, Lq, LenIn);

    // ---- MEGA-GEMM 2: output projections, grid (85, 3) ----
    {
        SegParams p;
        // seg0: out[:, :256] = ct @ W_out, N=256 -> y 0..1
        p.seg[0] = { ct, nullptr, DM, 0, dsts[4], nullptr, 384,
                     b_out, out, DM, 384, 0 };
        // seg1: out[:, 256:] = cb @ W_out_zd, N=128 -> y 2
        p.seg[1] = { cb, nullptr, DM, 0, dsts[5], nullptr, 384,
                     b_out_zd, out + U2, DM, 384, 0 };
        p.ystart[0] = 0; p.ystart[1] = 2;
        p.nseg = 2;
        gemm_seg_kernel<<<dim3(mg, 3), blk, 0, stream>>>(p);
    }
}

// Round 5
// 247.803 us; speedup vs baseline: 1.8192x; 1.1080x over previous
//
#include <hip/hip_runtime.h>
#include <hip/hip_bf16.h>
#include <math.h>

// Problem constants: N=2, D=384, 2U=256, nH=8, hd=48, nL=4, nP=4
#define DM   384
#define U2   256
#define HD   48

typedef __attribute__((ext_vector_type(8))) short short8;   // 8 bf16 = 4 VGPR
typedef __attribute__((ext_vector_type(4))) float floatx4;  // MFMA acc

static __device__ __forceinline__ unsigned short f2bfbits(float f) {
    __hip_bfloat16 h = __float2bfloat16(f);
    return *reinterpret_cast<unsigned short*>(&h);
}
static __device__ __forceinline__ unsigned pack2(float x, float y) {
    return (unsigned)f2bfbits(x) | ((unsigned)f2bfbits(y) << 16);
}
static __device__ __forceinline__ float bflo(unsigned u) { return __uint_as_float(u << 16); }
static __device__ __forceinline__ float bfhi(unsigned u) { return __uint_as_float(u & 0xffff0000u); }

// =====================================================================
// Prep: query->bf16, flat->bf16, 7 weight transposes (fp32->bf16).
// =====================================================================
struct PrepParams {
    const float* q; const float* f;
    __hip_bfloat16 *q_bf, *f_bf;
    const float* wsrc[7]; __hip_bfloat16* wdst[7];
    int K[7], N[7], off[8];
    int nQ4, nF4, total;
};
__global__ __launch_bounds__(256) void prep_kernel(PrepParams d) {
    const int idx = blockIdx.x * 256 + threadIdx.x;
    if (idx >= d.total) return;
    if (idx < d.nQ4) {
        const int i4 = idx * 4;
        const float4 v = *(const float4*)&d.q[i4];
        uint2 pk; pk.x = pack2(v.x, v.y); pk.y = pack2(v.z, v.w);
        *(uint2*)&d.q_bf[i4] = pk;
        return;
    }
    if (idx < d.nQ4 + d.nF4) {
        const int i4 = (idx - d.nQ4) * 4;
        const float4 v = *(const float4*)&d.f[i4];
        uint2 pk; pk.x = pack2(v.x, v.y); pk.y = pack2(v.z, v.w);
        *(uint2*)&d.f_bf[i4] = pk;
        return;
    }
    const int iw = idx - d.nQ4 - d.nF4;
    int s = 0;
#pragma unroll
    for (int i = 1; i < 7; ++i) if (iw >= d.off[i]) s = i;
    const int r = iw - d.off[s];
    const int k = r / d.N[s], n = r - k * d.N[s];
    d.wdst[s][(size_t)n * d.K[s] + k] = __float2bfloat16(d.wsrc[s][r]);
}

// =====================================================================
// Multi-segment bf16 MFMA GEMM. Segment picked by blockIdx.y range
// (switch with constant indices -> no scratch copy of the seg array).
// C(M x N) = A_bf16(M x K) @ Bt_bf16(N x K)^T + bias. 128x128 tile, BK=32.
// omode: 0 = f32 out; 1 = bf16 out (row-major ldc);
//        2/3 = bf16 scatter into combined value layout (top/bot):
//              idx = row*768 + (col/48)*96 + (omode==3)*48 + col%48
// 2-stage pipeline: global->regs prefetch overlaps MFMA.
// =====================================================================
struct Seg {
    const __hip_bfloat16* A; int lda;
    const __hip_bfloat16* Bt; int ldbt;
    const float* bias; void* C; int ldc; int K; int omode;
};
struct SegParams { Seg seg[5]; int ystart[5]; int nseg; };

__global__ __launch_bounds__(256) void gemm_seg_kernel(SegParams p) {
    __shared__ __hip_bfloat16 Ah[128 * 40];
    __shared__ __hip_bfloat16 Bh[128 * 40];

    const int yb = blockIdx.y;
    int s = 0;
#pragma unroll
    for (int i = 1; i < 5; ++i) if (i < p.nseg && yb >= p.ystart[i]) s = i;
    Seg sg;
    switch (s) {
        case 0: sg = p.seg[0]; break;
        case 1: sg = p.seg[1]; break;
        case 2: sg = p.seg[2]; break;
        case 3: sg = p.seg[3]; break;
        default: sg = p.seg[4]; break;
    }
    const int by = yb - p.ystart[s];

    const int t    = threadIdx.x;
    const int bm   = blockIdx.x * 128;
    const int bn   = by * 128;
    const int w    = t >> 6, lane = t & 63;
    const int wm   = (w >> 1) * 64, wn = (w & 1) * 64;
    const int quad = lane >> 4, lm = lane & 15;

    const int r0 = t >> 2, kc = (t & 3) * 8;

    const __hip_bfloat16* Aptr0 = sg.A  + (size_t)(bm + r0) * sg.lda  + kc;
    const __hip_bfloat16* Aptr1 = sg.A  + (size_t)(bm + r0 + 64) * sg.lda  + kc;
    const __hip_bfloat16* Bptr0 = sg.Bt + (size_t)(bn + r0) * sg.ldbt + kc;
    const __hip_bfloat16* Bptr1 = sg.Bt + (size_t)(bn + r0 + 64) * sg.ldbt + kc;

    short8 aR0 = *(const short8*)Aptr0;
    short8 aR1 = *(const short8*)Aptr1;
    short8 bR0 = *(const short8*)Bptr0;
    short8 bR1 = *(const short8*)Bptr1;

    floatx4 acc[4][4] = {};

    for (int k0 = 0; k0 < sg.K; k0 += 32) {
        *(short8*)&Ah[r0 * 40 + kc]        = aR0;
        *(short8*)&Ah[(r0 + 64) * 40 + kc] = aR1;
        *(short8*)&Bh[r0 * 40 + kc]        = bR0;
        *(short8*)&Bh[(r0 + 64) * 40 + kc] = bR1;
        __syncthreads();

        const int kn = k0 + 32;
        if (kn < sg.K) {
            aR0 = *(const short8*)(Aptr0 + kn);
            aR1 = *(const short8*)(Aptr1 + kn);
            bR0 = *(const short8*)(Bptr0 + kn);
            bR1 = *(const short8*)(Bptr1 + kn);
        }

        short8 af[4], bf[4];
#pragma unroll
        for (int i = 0; i < 4; ++i)
            af[i] = *(const short8*)&Ah[(wm + i * 16 + lm) * 40 + quad * 8];
#pragma unroll
        for (int j = 0; j < 4; ++j)
            bf[j] = *(const short8*)&Bh[(wn + j * 16 + lm) * 40 + quad * 8];
#pragma unroll
        for (int i = 0; i < 4; ++i)
#pragma unroll
            for (int j = 0; j < 4; ++j)
                acc[i][j] = __builtin_amdgcn_mfma_f32_16x16x32_bf16(
                    af[i], bf[j], acc[i][j], 0, 0, 0);
        __syncthreads();
    }

#pragma unroll
    for (int i = 0; i < 4; ++i)
#pragma unroll
        for (int reg = 0; reg < 4; ++reg) {
            const int row = bm + wm + i * 16 + quad * 4 + reg;
#pragma unroll
            for (int j = 0; j < 4; ++j) {
                const int col = bn + wn + j * 16 + lm;
                const float v = acc[i][j][reg] + sg.bias[col];
                if (sg.omode == 0) {
                    ((float*)sg.C)[(size_t)row * sg.ldc + col] = v;
                } else if (sg.omode == 1) {
                    ((__hip_bfloat16*)sg.C)[(size_t)row * sg.ldc + col] = __float2bfloat16(v);
                } else {
                    const int h = col / 48;
                    const size_t idx = (size_t)row * 768 + h * 96 +
                                       ((sg.omode == 3) ? 48 : 0) + (col - h * 48);
                    ((__hip_bfloat16*)sg.C)[idx] = __float2bfloat16(v);
                }
            }
        }
}

// =====================================================================
// Fused sampler, 2 queries per 192-thread block.
// Phase 1: geometry in regs (itemA: t<128 -> q0; itemB: t>=64 -> q1).
// Softmax: t<32 reads logits from global, writes sA.
// Phase 2.5: pack (bf16(w*attn)<<16 | point) into sP.
// Phase 3: 96 threads/query; group = (br,h) of 6 threads, uint4 gathers
// from combined value layout (point row = 1536B = [h][br][48ch]).
// 12 consecutive lanes read one contiguous 192B segment (3 cache lines).
// =====================================================================
#define SPP 524   // per (q,br) sP stride

__global__ __launch_bounds__(192) void sampler_kernel(
    const float* __restrict__ off_buf,    // (M, 256) fp32
    const float* __restrict__ logit_top,  // (M, 128)
    const float* __restrict__ logit_bot,  // (M, 128)
    const float* __restrict__ ref_pts,    // (M, 4, 2)
    const int*   __restrict__ ss,         // (4,2) [H,W]
    const int*   __restrict__ lsi,        // (4,)
    const __hip_bfloat16* __restrict__ vcomb,  // (Mv, 768) combined
    __hip_bfloat16* __restrict__ core_top,     // (M, 384) bf16
    __hip_bfloat16* __restrict__ core_bot,     // (M, 384) bf16
    int Lq, int LenIn)
{
    __shared__ float    sA[4][128];   // [q*2+br][e] softmaxed attn
    __shared__ unsigned sP[4][SPP];   // packed (bf16 w)<<16 | point

    const int bid = blockIdx.x;
    const int Q0  = bid * 2;
    const int t   = threadIdx.x;

    // ---- phase 1: geometry (registers only) ----
    float gw[2][4];
    int   gp[2][4];
#pragma unroll
    for (int slot = 0; slot < 2; ++slot) {
        const bool active = slot ? (t >= 64) : (t < 128);
        if (!active) continue;
        const int qL = slot;
        const int e  = slot ? (t - 64) : t;
        const int gq = Q0 + qL;
        const int n  = gq / Lq;
        const int l  = (e >> 2) & 3;
        const float2 offv = *(const float2*)&off_buf[(size_t)gq * 256 + 2 * e];
        const float rx = ref_pts[(size_t)(gq * 4 + l) * 2 + 0];
        const float ry = ref_pts[(size_t)(gq * 4 + l) * 2 + 1];
        const int H = ss[2 * l], W = ss[2 * l + 1];
        const int start = lsi[l];

        const float x = (rx + offv.x / (float)W) * (float)W - 0.5f;
        const float y = (ry + offv.y / (float)H) * (float)H - 0.5f;
        const float x0f = floorf(x), y0f = floorf(y);
        const float lx = x - x0f, ly = y - y0f;
        const int ix0 = (int)x0f, iy0 = (int)y0f;
        const int ix1 = ix0 + 1,  iy1 = iy0 + 1;

        const float vx0 = (ix0 >= 0 && ix0 < W) ? 1.f : 0.f;
        const float vx1 = (ix1 >= 0 && ix1 < W) ? 1.f : 0.f;
        const float vy0 = (iy0 >= 0 && iy0 < H) ? 1.f : 0.f;
        const float vy1 = (iy1 >= 0 && iy1 < H) ? 1.f : 0.f;
        const int cx0 = min(max(ix0, 0), W - 1);
        const int cx1 = min(max(ix1, 0), W - 1);
        const int cy0 = min(max(iy0, 0), H - 1);
        const int cy1 = min(max(iy1, 0), H - 1);
        const int base = n * LenIn + start;

        gp[slot][0] = base + cy0 * W + cx0;
        gp[slot][1] = base + cy0 * W + cx1;
        gp[slot][2] = base + cy1 * W + cx0;
        gp[slot][3] = base + cy1 * W + cx1;
        gw[slot][0] = (1.f - lx) * (1.f - ly) * vx0 * vy0;
        gw[slot][1] = lx * (1.f - ly) * vx1 * vy0;
        gw[slot][2] = (1.f - lx) * ly * vx0 * vy1;
        gw[slot][3] = lx * ly * vx1 * vy1;
    }

    // ---- softmax (no dependence on phase 1) ----
    if (t < 32) {
        const int q  = t >> 4;
        const int br = (t >> 3) & 1;
        const int h  = t & 7;
        const float* L = (br ? logit_bot : logit_top) + (size_t)(Q0 + q) * 128 + h * 16;
        float lg[16];
        *(float4*)&lg[0]  = *(const float4*)&L[0];
        *(float4*)&lg[4]  = *(const float4*)&L[4];
        *(float4*)&lg[8]  = *(const float4*)&L[8];
        *(float4*)&lg[12] = *(const float4*)&L[12];
        float m = -1e30f;
#pragma unroll
        for (int j = 0; j < 16; ++j) m = fmaxf(m, lg[j]);
        float ex[16], sum = 0.f;
#pragma unroll
        for (int j = 0; j < 16; ++j) { ex[j] = expf(lg[j] - m); sum += ex[j]; }
        const float inv = 1.f / sum;
#pragma unroll
        for (int j = 0; j < 16; ++j) sA[q * 2 + br][h * 16 + j] = ex[j] * inv;
    }
    __syncthreads();

    // ---- phase 2.5: pack premultiplied weights + point indices ----
#pragma unroll
    for (int slot = 0; slot < 2; ++slot) {
        const bool active = slot ? (t >= 64) : (t < 128);
        if (!active) continue;
        const int e = slot ? (t - 64) : t;
        const int pidx = 4 * e + (e >> 4);
#pragma unroll
        for (int br = 0; br < 2; ++br) {
            const float a = sA[slot * 2 + br][e];
#pragma unroll
            for (int k = 0; k < 4; ++k) {
                sP[slot * 2 + br][pidx + k] =
                    ((unsigned)f2bfbits(gw[slot][k] * a) << 16) | (unsigned)gp[slot][k];
            }
        }
    }
    __syncthreads();

    // ---- phase 3: gathers ----
    const int q  = t / 96;
    const int r  = t - q * 96;
    const int g  = r / 6;
    const int m  = r - g * 6;
    const int br = g & 1;
    const int h  = g >> 1;

    const unsigned* P = sP[q * 2 + br];
    const char* vb = (const char*)vcomb + h * 192 + br * 96 + m * 16;

    float a0 = 0.f, a1 = 0.f, a2 = 0.f, a3 = 0.f;
    float a4 = 0.f, a5 = 0.f, a6 = 0.f, a7 = 0.f;
#pragma unroll 4
    for (int lp = 0; lp < 16; ++lp) {
        const int ib = 65 * h + 4 * lp;
#pragma unroll
        for (int k = 0; k < 4; ++k) {
            const unsigned u = P[ib + k];
            const float wv = __uint_as_float(u & 0xffff0000u);
            const unsigned pt = u & 0x3fffu;
            const uint4 v = *(const uint4*)(vb + pt * 1536u);
            a0 = fmaf(wv, bflo(v.x), a0);
            a1 = fmaf(wv, bfhi(v.x), a1);
            a2 = fmaf(wv, bflo(v.y), a2);
            a3 = fmaf(wv, bfhi(v.y), a3);
            a4 = fmaf(wv, bflo(v.z), a4);
            a5 = fmaf(wv, bfhi(v.z), a5);
            a6 = fmaf(wv, bflo(v.w), a6);
            a7 = fmaf(wv, bfhi(v.w), a7);
        }
    }
    uint4 o;
    o.x = pack2(a0, a1); o.y = pack2(a2, a3);
    o.z = pack2(a4, a5); o.w = pack2(a6, a7);
    __hip_bfloat16* dst = br ? core_bot : core_top;
    *(uint4*)&dst[(size_t)(Q0 + q) * DM + h * HD + m * 8] = o;
}

// =====================================================================
// Host launcher
// =====================================================================
extern "C" void kernel_launch(void* const* d_in, const int* in_sizes, int n_in,
                              void* d_out, int out_size, void* d_ws, size_t ws_size,
                              hipStream_t stream) {
    const float* query   = (const float*)d_in[0];
    const float* refpts  = (const float*)d_in[1];
    const float* flat    = (const float*)d_in[2];
    const int*   ss      = (const int*)d_in[3];
    const int*   lsi     = (const int*)d_in[4];
    const float* W_off   = (const float*)d_in[5];
    const float* b_off   = (const float*)d_in[6];
    const float* W_attn  = (const float*)d_in[7];
    const float* b_attn  = (const float*)d_in[8];
    const float* W_val   = (const float*)d_in[9];
    const float* b_val   = (const float*)d_in[10];
    const float* W_out   = (const float*)d_in[11];
    const float* b_out   = (const float*)d_in[12];
    const float* W_attn_zd = (const float*)d_in[13];
    const float* b_attn_zd = (const float*)d_in[14];
    const float* W_val_zd  = (const float*)d_in[15];
    const float* b_val_zd  = (const float*)d_in[16];
    const float* W_out_zd  = (const float*)d_in[17];
    const float* b_out_zd  = (const float*)d_in[18];

    const int Lq    = in_sizes[0] / (2 * DM);   // 5440
    const int LenIn = in_sizes[2] / (2 * DM);   // 5440
    const int M  = 2 * Lq;      // 10880
    const int Mv = 2 * LenIn;   // 10880

    float* out = (float*)d_out;

    // ---- workspace layout ----
    float* ws      = (float*)d_ws;
    float* off_buf = ws;                               // M*256 f32
    float* lt      = off_buf + (size_t)M * 256;        // M*128 f32
    float* lb      = lt + (size_t)M * 128;             // M*128 f32
    __hip_bfloat16* q_bf  = (__hip_bfloat16*)(lb + (size_t)M * 128); // M*384
    __hip_bfloat16* f_bf  = q_bf + (size_t)M * 384;    // Mv*384
    __hip_bfloat16* vcomb = f_bf + (size_t)Mv * 384;   // Mv*768 combined
    __hip_bfloat16* ct    = vcomb + (size_t)Mv * 768;  // M*384
    __hip_bfloat16* cb    = ct + (size_t)M * 384;      // M*384
    __hip_bfloat16* wtb   = cb + (size_t)M * 384;      // weights

    // ---- prep params (7 weight transposes incl. W_off) ----
    PrepParams pp;
    pp.q = query; pp.f = flat;
    pp.q_bf = q_bf; pp.f_bf = f_bf;
    const float* srcs[7] = {W_attn, W_attn_zd, W_val, W_val_zd, W_out, W_out_zd, W_off};
    const int Ks[7] = {256, 384, 256, 384, 384, 384, 256};
    const int Ns[7] = {128, 128, 384, 384, 256, 128, 256};
    __hip_bfloat16* dsts[7];
    int off = 0;
    for (int i = 0; i < 7; ++i) {
        pp.wsrc[i] = srcs[i]; pp.K[i] = Ks[i]; pp.N[i] = Ns[i];
        pp.off[i] = off;
        dsts[i] = wtb + off;
        pp.wdst[i] = dsts[i];
        off += Ks[i] * Ns[i];
    }
    pp.off[7] = off;
    pp.nQ4 = M * DM / 4;
    pp.nF4 = Mv * DM / 4;
    pp.total = pp.nQ4 + pp.nF4 + off;

    const dim3 blk(256);
    const int mg = M / 128;   // 85

    prep_kernel<<<dim3((pp.total + 255) / 256), blk, 0, stream>>>(pp);

    // ---- MEGA-GEMM 1: off + logits + values(combined scatter), grid (85,10)
    {
        SegParams p;
        p.seg[0] = { q_bf, DM, dsts[6], 256, b_off,    off_buf, 256, 256, 0 }; // y0-1
        p.seg[1] = { q_bf, DM, dsts[0], 256, b_attn,   lt,      128, 256, 0 }; // y2
        p.seg[2] = { q_bf, DM, dsts[1], 384, b_attn_zd,lb,      128, 384, 0 }; // y3
        p.seg[3] = { f_bf, DM, dsts[2], 256, b_val,    vcomb,   0,   256, 2 }; // y4-6 top
        p.seg[4] = { f_bf, DM, dsts[3], 384, b_val_zd, vcomb,   0,   384, 3 }; // y7-9 bot
        p.ystart[0] = 0; p.ystart[1] = 2; p.ystart[2] = 3;
        p.ystart[3] = 4; p.ystart[4] = 7;
        p.nseg = 5;
        gemm_seg_kernel<<<dim3(mg, 10), blk, 0, stream>>>(p);
    }

    // ---- sampler: 2 queries per block ----
    sampler_kernel<<<dim3(M / 2), dim3(192), 0, stream>>>(
        off_buf, lt, lb, refpts, ss, lsi, vcomb, ct, cb, Lq, LenIn);

    // ---- MEGA-GEMM 2: output projections, grid (85,3) ----
    {
        SegParams p;
        p.seg[0] = { ct, DM, dsts[4], 384, b_out,    out,      DM, 384, 0 }; // y0-1
        p.seg[1] = { cb, DM, dsts[5], 384, b_out_zd, out + U2, DM, 384, 0 }; // y2
        p.ystart[0] = 0; p.ystart[1] = 2;
        p.nseg = 2;
        gemm_seg_kernel<<<dim3(mg, 3), blk, 0, stream>>>(p);
    }
}